// Round 4
// baseline (1911.516 us; speedup 1.0000x reference)
//
#include <hip/hip_runtime.h>
#include <hip/hip_bf16.h>

typedef unsigned short u16;
typedef unsigned int   u32;
typedef __attribute__((ext_vector_type(8))) short bf16x8;
typedef __attribute__((ext_vector_type(4))) short bf16x4;
typedef __attribute__((ext_vector_type(4))) float f32x4;

#define NH   16
#define SS   2048

__device__ __forceinline__ u16 bf16b(float f) {
  union { float f; u32 u; } v; v.f = f;
  u32 r = (v.u + 0x7fffu + ((v.u >> 16) & 1u)) >> 16;
  return (u16)r;
}
__device__ __forceinline__ float bf2f(u16 v) {
  union { u32 u; float f; } x; x.u = (u32)v << 16; return x.f;
}
__device__ __forceinline__ f32x4 mfma16(bf16x8 a, bf16x8 b, f32x4 c) {
  return __builtin_amdgcn_mfma_f32_16x16x32_bf16(a, b, c, 0, 0, 0);
}
// K=16 PV MFMA (2-reg operands). ISA: v_mfma_f32_16x16x16_bf16.
__device__ __forceinline__ f32x4 mfma16k16(bf16x4 a, bf16x4 b, f32x4 c) {
#if __has_builtin(__builtin_amdgcn_mfma_f32_16x16x16bf16_1k)
  return __builtin_amdgcn_mfma_f32_16x16x16bf16_1k(a, b, c, 0, 0, 0);
#else
  f32x4 d;
  asm volatile("v_mfma_f32_16x16x16_bf16 %0, %1, %2, %3"
               : "=v"(d) : "v"(a), "v"(b), "v"(c));
  return d;
#endif
}
// async global->LDS DMA, 16B per lane: LDS dest = wave-uniform base + lane*16B,
// global src per-lane (carries the swizzle).
__device__ __forceinline__ void gl_lds16(const u16* g, u16* l) {
  __builtin_amdgcn_global_load_lds(
      (const __attribute__((address_space(1))) void*)g,
      (__attribute__((address_space(3))) void*)l, 16, 0, 0);
}

// ---------------------------------------------------------------- zero-fill (ws-too-small signature)
__global__ __launch_bounds__(256) void zerok(float* __restrict__ p, long n)
{
  long i = ((long)blockIdx.x * 256 + threadIdx.x) * 4;
  if (i < n) { p[i] = 0.f; p[i+1] = 0.f; p[i+2] = 0.f; p[i+3] = 0.f; }
}

// ---------------------------------------------------------------- cast fp32->bf16
__global__ __launch_bounds__(256) void castk(const float* __restrict__ src,
                                             u16* __restrict__ dst, long n)
{
  long i = ((long)blockIdx.x * 256 + threadIdx.x) * 4;
  if (i >= n) return;
  const float4 f = *(const float4*)(src + i);
  uint2 v;
  v.x = (u32)bf16b(f.x) | ((u32)bf16b(f.y) << 16);
  v.y = (u32)bf16b(f.z) | ((u32)bf16b(f.w) << 16);
  *(uint2*)(dst + i) = v;
}

// ---------------------------------------------------------------- split wkv_b
__global__ __launch_bounds__(256) void wsplit(const float* __restrict__ wb,
                                              u16* __restrict__ T1, u16* __restrict__ Wv)
{
  const long i = (long)blockIdx.x * 256 + threadIdx.x;   // < 16*65536
  const int h   = (int)(i >> 16);
  const int rem = (int)(i & 65535);
  { const int c = rem >> 7, d = rem & 127;
    T1[i] = bf16b(wb[((long)(h * 256 + d)) * 512 + c]); }
  { const int d = rem >> 9, c = rem & 511;
    Wv[i] = bf16b(wb[((long)(h * 256 + 128 + d)) * 512 + c]); }
}

// ---------------------------------------------------------------- generic bf16 GEMM  C = A @ W^T
template<int OUTBF>
__global__ __launch_bounds__(256, 2)
void gemm_bt(const u16* __restrict__ A, const u16* __restrict__ W, void* __restrict__ Cout,
             int M, int N, int K, int lda, int ldw, int ldc,
             long aStride, long wStride, long cStride)
{
  __shared__ u16 As[128 * 40];
  __shared__ u16 Bs[128 * 40];
  const int tid = threadIdx.x;
  const int wave = tid >> 6, lane = tid & 63, g = lane >> 4, l15 = lane & 15;
  const int z = blockIdx.z;
  A += (long)z * aStride;  W += (long)z * wStride;
  const long cOff = (long)z * cStride;
  const int m0 = blockIdx.y * 128, n0 = blockIdx.x * 128;
  const int mq = (wave >> 1) * 64, nq = (wave & 1) * 64;
  const int srow = tid >> 1, scol = (tid & 1) * 16;

  const f32x4 fzero = {0.f, 0.f, 0.f, 0.f};
  f32x4 acc[4][4];
#pragma unroll
  for (int i = 0; i < 4; i++)
#pragma unroll
    for (int j = 0; j < 4; j++) acc[i][j] = fzero;

  for (int k0 = 0; k0 < K; k0 += 32) {
    const u16* aSrc = A + (long)(m0 + srow) * lda + k0 + scol;
    uint4 av0 = *(const uint4*)aSrc;
    uint4 av1 = *(const uint4*)(aSrc + 8);
    uint4 bv0 = make_uint4(0, 0, 0, 0), bv1 = make_uint4(0, 0, 0, 0);
    if (n0 + srow < N) {
      const u16* wSrc = W + (long)(n0 + srow) * ldw + k0 + scol;
      bv0 = *(const uint4*)wSrc;
      bv1 = *(const uint4*)(wSrc + 8);
    }
    __syncthreads();
    *(uint4*)&As[srow * 40 + scol]     = av0;
    *(uint4*)&As[srow * 40 + scol + 8] = av1;
    *(uint4*)&Bs[srow * 40 + scol]     = bv0;
    *(uint4*)&Bs[srow * 40 + scol + 8] = bv1;
    __syncthreads();

    bf16x8 af[4], bfr[4];
#pragma unroll
    for (int i = 0; i < 4; i++) af[i]  = *(const bf16x8*)&As[(mq + i * 16 + l15) * 40 + g * 8];
#pragma unroll
    for (int j = 0; j < 4; j++) bfr[j] = *(const bf16x8*)&Bs[(nq + j * 16 + l15) * 40 + g * 8];
#pragma unroll
    for (int i = 0; i < 4; i++)
#pragma unroll
      for (int j = 0; j < 4; j++)
        acc[i][j] = mfma16(af[i], bfr[j], acc[i][j]);
  }

#pragma unroll
  for (int i = 0; i < 4; i++) {
    const int r0 = m0 + mq + i * 16 + g * 4;
#pragma unroll
    for (int j = 0; j < 4; j++) {
      const int c = n0 + nq + j * 16 + l15;
      if (c < N) {
#pragma unroll
        for (int r = 0; r < 4; r++) {
          const long idx = cOff + (long)(r0 + r) * ldc + c;
          if (OUTBF) ((u16*)Cout)[idx]   = bf16b(acc[i][j][r]);
          else       ((float*)Cout)[idx] = acc[i][j][r];
        }
      }
    }
  }
}

// ---------------------------------------------------------------- q rope pack
__global__ __launch_bounds__(256) void qpack(const u16* __restrict__ q,
                                             const float* __restrict__ angles,
                                             u16* __restrict__ qpe)
{
  const int s = blockIdx.x;
  const int sseq = s & (SS - 1);
  const int tid = threadIdx.x;
#pragma unroll
  for (int pp = 0; pp < 2; pp++) {
    const int p = tid * 2 + pp;           // 0..511 pair index
    const int h = p >> 5, j = p & 31;
    const float xr = bf2f(q[(long)s * 3072 + h * 192 + 128 + 2 * j]);
    const float xi = bf2f(q[(long)s * 3072 + h * 192 + 128 + 2 * j + 1]);
    float sn, cs;
    __sincosf(angles[sseq * 32 + j], &sn, &cs);
    const u32 pk = (u32)bf16b(xr * cs - xi * sn) | ((u32)bf16b(xr * sn + xi * cs) << 16);
    *(u32*)(qpe + ((long)s * NH + h) * 64 + 2 * j) = pk;
  }
}

// ---------------------------------------------------------------- kv pack
__global__ __launch_bounds__(256) void kvpack(const u16* __restrict__ kv,
                                              const float* __restrict__ angles,
                                              const float* __restrict__ kvw,
                                              u16* __restrict__ cb, u16* __restrict__ kpe)
{
  const int row = blockIdx.x * 4 + (threadIdx.x >> 6);
  const int lane = threadIdx.x & 63;
  const int sseq = row & (SS - 1);
  const u16* src = kv + (long)row * 576;
  float v[8]; float ss = 0.f;
#pragma unroll
  for (int j = 0; j < 8; j++) { float t = bf2f(src[lane + j * 64]); v[j] = t; ss += t * t; }
#pragma unroll
  for (int d = 1; d < 64; d <<= 1) ss += __shfl_xor(ss, d, 64);
  const float rn = 1.0f / sqrtf(ss * (1.f / 512.f) + 1e-6f);
#pragma unroll
  for (int j = 0; j < 8; j++)
    cb[(long)row * 512 + lane + j * 64] = bf16b(v[j] * rn * kvw[lane + j * 64]);
  if (lane < 32) {
    const float xr = bf2f(src[512 + 2 * lane]), xi = bf2f(src[512 + 2 * lane + 1]);
    float sn, cs;
    __sincosf(angles[sseq * 32 + lane], &sn, &cs);
    const u32 pk = (u32)bf16b(xr * cs - xi * sn) | ((u32)bf16b(xr * sn + xi * cs) << 16);
    *(u32*)(kpe + (long)row * 64 + 2 * lane) = pk;
  }
}

// ---------------------------------------------------------------- MFMA flash attention
// R2 skeleton (aligned t across all co-resident blocks -> K staging L2-hits)
// + HEAVY-FIRST dispatch: bx = 31 - blockIdx.x. Longest-job-first makes
// makespan ~= max(ideal 132, longest 128) instead of light-first's 132+128.
// Refill blocks are light ones reading early (hottest) tiles -> alignment kept.
// K tile double-buffered via global_load_lds DMA (content pre-swizzled on the
// per-lane GLOBAL address): KsD[t'][q] holds cb[t'][q ^ sw(t')],
// sw(t') = ((t'>>1)&7)<<3. Raw s_barrier + vmcnt(0) at the consume point only.
// PV uses K=16 MFMA (v_mfma_f32_16x16x16_bf16): no zero-padding anywhere ->
// VT16 [512][16] fully written each step, Ps all real, NO zero-init.
// VT16 bijective swizzle: idx = (c*16 + t') ^ (((c>>4)&7)<<3); build writes
// 2-way (free), PV b64 reads at the floor (verified by bank arithmetic).
// Region layout = R2's (VT build alone between barriers; S/softmax/PV after
// barrier2) -- R3's mixing of S-reads with VT-writes 4x'd conflicts/CU-step.
__global__ __launch_bounds__(256, 2)
void attn_flash(const u16* __restrict__ qab, const u16* __restrict__ qpe,
                const u16* __restrict__ cb, const u16* __restrict__ kpe,
                u16* __restrict__ olat)
{
  __shared__ u16 KsD[2][16 * 512];   // 32768 B  K c-part, dbuf, content-swizzled
  __shared__ u16 KrD[2][16 * 64];    //  4096 B  K rope,  dbuf, content-swizzled
  __shared__ u16 VT16[512 * 16];     // 16384 B  [c][t'] bijective-swizzled, all real
  __shared__ u16 Ps[4][16 * 20];     //  2560 B  per-wave P[s'][t'], stride 20

  const int tid = threadIdx.x;
  const int wave = tid >> 6, lane = tid & 63;
  const int g = lane >> 4, l15 = lane & 15;
  const int bh = blockIdx.y, b = bh >> 4, h = bh & 15;
  const int bx = (int)gridDim.x - 1 - (int)blockIdx.x;   // heavy blocks dispatch first
  const int s0 = bx * 64;
  const int swave = s0 + wave * 16;
  const float NEG_INF = -__builtin_inff();
  const float SC = 0.07216878364870323f * 1.3688879454113936f * 1.3688879454113936f;
  const f32x4 fzero = {0.f, 0.f, 0.f, 0.f};

  // Q A-fragments: A[m=l15][k=g*8+j], k over 576 = 18 frags
  bf16x8 qf[18];
  {
    const u16* qa = qab + ((long)(b * SS + swave + l15) * NH + h) * 512;
#pragma unroll
    for (int f = 0; f < 16; f++) qf[f] = *(const bf16x8*)(qa + f * 32 + g * 8);
    const u16* qp = qpe + ((long)(b * SS + swave + l15) * NH + h) * 64;
    qf[16] = *(const bf16x8*)(qp + g * 8);
    qf[17] = *(const bf16x8*)(qp + 32 + g * 8);
  }

  f32x4 oacc[32];                 // O[s'=g*4+r][c=i*16+l15]
#pragma unroll
  for (int i = 0; i < 32; i++) oacc[i] = fzero;
  float m[4], l[4];
#pragma unroll
  for (int r = 0; r < 4; r++) { m[r] = NEG_INF; l[r] = 0.f; }

  const int nsteps  = 4 * bx + 4;
  const int lastact = 4 * bx + wave;   // last tile this wave needs

  const int tp   = tid & 7;        // VT build: t-pair 0..7
  const int cblk = tid >> 3;       // VT build: c-block 0..31 (16 c each)

  // ---- DMA issue for tile at row-offset t0n into buffer `buf` (wave-divided)
  auto stage = [&](int t0n, int buf) {
#pragma unroll
    for (int it = 0; it < 4; ++it) {
      const int tr = it * 4 + wave;                       // K row 0..15, 4 per wave
      const int sw = ((tr >> 1) & 7) << 3;
      const u16* gp = cb + (long)(b * SS + t0n + tr) * 512 + ((lane * 8) ^ sw);
      gl_lds16(gp, &KsD[buf][tr * 512]);                  // lane fills 16B chunk lane
    }
    if (wave < 2) {                                        // rope: 8 rows per wave
      const int r0 = wave * 8;
      const int tr = r0 + (lane >> 3);
      const int sw = ((tr >> 1) & 7) << 3;
      const u16* gp = kpe + (long)(b * SS + t0n + tr) * 64 + (((lane & 7) * 8) ^ sw);
      gl_lds16(gp, &KrD[buf][r0 * 64]);
    }
  };

  stage(0, 0);                      // prologue: tile 0 -> buf 0

  for (int ts = 0; ts < nsteps; ++ts) {
    const int cur = ts & 1;
    const int t0 = ts * 16;
    // consume point: own DMA landed; barrier makes all waves' DMA + prior
    // compute (last readers of VT16 and KsD[cur^1]) visible.
    asm volatile("s_waitcnt vmcnt(0) lgkmcnt(0)" ::: "memory");
    __builtin_amdgcn_s_barrier();

    if (ts + 1 < nsteps) stage(t0 + 16, cur ^ 1);   // prefetch; in flight through compute

    // ---- build VT16 from resident K tile (LDS->LDS transpose, static scatter)
    {
      const u16* K0 = &KsD[cur][(2 * tp) * 512];
      const u16* K1 = &KsD[cur][(2 * tp + 1) * 512];
      const int swr  = (tp & 7) << 3;                 // sw(2tp) == sw(2tp+1)
      const int cb16 = cblk * 16;
      const bf16x8 alo = *(const bf16x8*)&K0[(cb16)     ^ swr];
      const bf16x8 ahi = *(const bf16x8*)&K0[(cb16 + 8) ^ swr];
      const bf16x8 blo = *(const bf16x8*)&K1[(cb16)     ^ swr];
      const bf16x8 bhi = *(const bf16x8*)&K1[(cb16 + 8) ^ swr];
#pragma unroll
      for (int j = 0; j < 16; ++j) {                  // j static -> register extracts
        const int c = cb16 + j;
        const u16 ua = (u16)((j < 8) ? alo[j] : ahi[j - 8]);
        const u16 ub = (u16)((j < 8) ? blo[j] : bhi[j - 8]);
        *(u32*)&VT16[(c * 16 + 2 * tp) ^ ((cblk & 7) << 3)] = (u32)ua | ((u32)ub << 16);
      }
    }
    asm volatile("s_waitcnt lgkmcnt(0)" ::: "memory");   // VT16 writes done (vmcnt untouched!)
    __builtin_amdgcn_s_barrier();

    if (ts > lastact) continue;        // wave-uniform; barriers still hit each iter

    // ---- S = Q K^T : dual accumulators halve the dependent-MFMA chain
    const int swl = ((l15 >> 1) & 7) << 3;
    const u16* KsC = &KsD[cur][l15 * 512];
    const u16* KrC = &KrD[cur][l15 * 64];
    f32x4 sacc = fzero, sacc2 = fzero;
    __builtin_amdgcn_s_setprio(1);
#pragma unroll
    for (int f = 0; f < 16; f += 2) {
      const bf16x8 k0 = *(const bf16x8*)&KsC[((f    ) * 32 + g * 8) ^ swl];
      const bf16x8 k1 = *(const bf16x8*)&KsC[((f + 1) * 32 + g * 8) ^ swl];
      sacc  = mfma16(qf[f],     k0, sacc);
      sacc2 = mfma16(qf[f + 1], k1, sacc2);
    }
    {
      const bf16x8 k0 = *(const bf16x8*)&KrC[(     g * 8) ^ swl];
      const bf16x8 k1 = *(const bf16x8*)&KrC[(32 + g * 8) ^ swl];
      sacc  = mfma16(qf[16], k0, sacc);
      sacc2 = mfma16(qf[17], k1, sacc2);
    }
    __builtin_amdgcn_s_setprio(0);

    // ---- online softmax with defer-max (THR=8): keep old m unless tile max
    // jumps by >8 -> rescale pass (below) skipped on most steps.
    float alf[4]; bool resc = false;
#pragma unroll
    for (int r = 0; r < 4; ++r) {
      const int srow = swave + g * 4 + r;
      float v = (sacc[r] + sacc2[r]) * SC;
      if (t0 + l15 > srow) v = NEG_INF;
      float tm = v;
#pragma unroll
      for (int d = 1; d < 16; d <<= 1) tm = fmaxf(tm, __shfl_xor(tm, d, 64));
      const float mnew = (tm > m[r] + 8.f) ? tm : m[r];   // m=-inf: -inf+8=-inf -> take tm
      const float al = __expf(m[r] - mnew);               // 1.0 when unchanged
      const float p  = __expf(v - mnew);                  // bounded by e^8; masked: 0
      float rs = p;
#pragma unroll
      for (int d = 1; d < 16; d <<= 1) rs += __shfl_xor(rs, d, 64);
      l[r] = l[r] * al + rs;
      resc |= (mnew != m[r]);
      m[r] = mnew;
      alf[r] = al;
      Ps[wave][(g * 4 + r) * 20 + l15] = bf16b(p);   // intra-wave LDS, no barrier
    }

    // ---- gated rescale (skipped when no row max moved anywhere in the wave)
    if (__any((int)resc)) {
#pragma unroll
      for (int i = 0; i < 32; ++i) {
        f32x4 o = oacc[i];
        o[0] *= alf[0]; o[1] *= alf[1]; o[2] *= alf[2]; o[3] *= alf[3];
        oacc[i] = o;
      }
    }

    // ---- O += P.V : K=16 MFMA, A=P[s'][t'], B[n=c][k=t'] from VT16
    const bf16x4 paf = *(const bf16x4*)&Ps[wave][l15 * 20 + g * 4];
    __builtin_amdgcn_s_setprio(1);
#pragma unroll
    for (int i = 0; i < 32; ++i) {
      const int c = i * 16 + l15;
      const bf16x4 vf = *(const bf16x4*)&VT16[(c * 16 + g * 4) ^ ((i & 7) << 3)];
      oacc[i] = mfma16k16(paf, vf, oacc[i]);
    }
    __builtin_amdgcn_s_setprio(0);
  }

  // ---- epilogue: O[s][c] / l[s]
  float linv[4];
#pragma unroll
  for (int r = 0; r < 4; ++r) linv[r] = 1.0f / l[r];
#pragma unroll
  for (int r = 0; r < 4; ++r) {
    u16* dst = olat + ((long)(b * SS + swave + g * 4 + r) * NH + h) * 512 + l15;
#pragma unroll
    for (int i = 0; i < 32; ++i)
      dst[i * 16] = bf16b(oacc[i][r] * linv[r]);
  }
}

// ---------------------------------------------------------------- launch
extern "C" void kernel_launch(void* const* d_in, const int* in_sizes, int n_in,
                              void* d_out, int out_size, void* d_ws, size_t ws_size,
                              hipStream_t stream)
{
  const float* x      = (const float*)d_in[0];
  const float* angles = (const float*)d_in[1];
  const float* wq     = (const float*)d_in[2];
  const float* wkv_a  = (const float*)d_in[3];
  const float* wkv_b  = (const float*)d_in[4];
  const float* wo     = (const float*)d_in[5];
  const float* kvw    = (const float*)d_in[6];

  // --- workspace plan (byte offsets; lifetimes audited against launch order) ---
  const size_t WS_NEED = 157810688;
  if (ws_size < WS_NEED) {           // observable signature: err == ref absmax (3.890625)
    zerok<<<dim3(8192), dim3(256), 0, stream>>>((float*)d_out, 8388608L);
    return;
  }
  char* base = (char*)d_ws;
  u16* xb   = (u16*)(base + 0);           // 16,777,216 B  [4096][2048]   dead after kv GEMM
  u16* kvb  = (u16*)(base + 16777216);    //  4,718,592 B  [4096][576]    dead after kvpack
  u16* wab  = (u16*)(base + 21495808);    //  2,359,296 B  [576][2048]    dead after kv GEMM
  u16* qab  = (u16*)(base + 0);           // 67,108,864 B  [4096][16][512]  (phase2 of A)
  u16* ob   = (u16*)(base + 0);           // 16,777,216 B  [4096][2048]     (phase3 of A)
  u16* qbf  = (u16*)(base + 67108864);    // 25,165,824 B  [4096][3072]   dead after absorb GEMM
  u16* T1   = (u16*)(base + 92274688);    //  2,097,152 B  [16][512][128] dead after absorb GEMM
  u16* wqb  = (u16*)(base + 94371840);    // 12,582,912 B  [3072][2048]   dead after q GEMM
  u16* olat = (u16*)(base + 67108864);    // 67,108,864 B  [4096][16][512]  (phase2 of B)
  u16* wob  = (u16*)(base + 134217728);   //  8,388,608 B  [2048][2048]
  u16* Wv   = (u16*)(base + 142606336);   //  2,097,152 B  [16][128][512]
  u16* qpe_ = (u16*)(base + 144703488);   //  8,388,608 B  [4096][16][64]
  u16* cbuf = (u16*)(base + 153092096);   //  4,194,304 B  [4096][512]
  u16* kpeb = (u16*)(base + 157286400);   //    524,288 B  [4096][64]

  castk<<<dim3(8192), dim3(256), 0, stream>>>(x, xb, 8388608L);
  castk<<<dim3(6144), dim3(256), 0, stream>>>(wq, wqb, 6291456L);
  castk<<<dim3(1152), dim3(256), 0, stream>>>(wkv_a, wab, 1179648L);
  castk<<<dim3(4096), dim3(256), 0, stream>>>(wo, wob, 4194304L);
  wsplit<<<dim3(4096), dim3(256), 0, stream>>>(wkv_b, T1, Wv);

  // q = x @ wq^T (bf16 out) ; kv = x @ wkv_a^T (bf16 out)
  gemm_bt<1><<<dim3(24, 32, 1), dim3(256), 0, stream>>>(
      xb, wqb, (void*)qbf, 4096, 3072, 2048, 2048, 2048, 3072, 0L, 0L, 0L);
  gemm_bt<1><<<dim3(5, 32, 1), dim3(256), 0, stream>>>(
      xb, wab, (void*)kvb, 4096, 576, 2048, 2048, 2048, 576, 0L, 0L, 0L);

  qpack<<<dim3(4096), dim3(256), 0, stream>>>(qbf, angles, qpe_);
  kvpack<<<dim3(1024), dim3(256), 0, stream>>>(kvb, angles, kvw, cbuf, kpeb);

  // q_abs[s][h][c] = q_nope[s][h][:] @ T1[h][c][:]
  gemm_bt<1><<<dim3(4, 32, 16), dim3(256), 0, stream>>>(
      qbf, T1, (void*)qab, 4096, 512, 128, 3072, 128, 8192, 192L, 65536L, 512L);

  attn_flash<<<dim3(32, 32), dim3(256), 0, stream>>>(qab, qpe_, cbuf, kpeb, olat);

  // o[s][h][d] = olat[s][h][:] @ Wv[h][d][:]
  gemm_bt<1><<<dim3(1, 32, 16), dim3(256), 0, stream>>>(
      olat, Wv, (void*)ob, 4096, 128, 512, 8192, 512, 2048, 512L, 65536L, 128L);

  // out = ob @ wo^T
  gemm_bt<0><<<dim3(16, 32, 1), dim3(256), 0, stream>>>(
      ob, wob, d_out, 4096, 2048, 2048, 2048, 2048, 2048, 0L, 0L, 0L);
}

// Round 5
// 1479.043 us; speedup vs baseline: 1.2924x; 1.2924x over previous
//
#include <hip/hip_runtime.h>
#include <hip/hip_bf16.h>

typedef unsigned short u16;
typedef unsigned int   u32;
typedef __attribute__((ext_vector_type(8))) short bf16x8;
typedef __attribute__((ext_vector_type(4))) float f32x4;

#define NH   16
#define SS   2048

__device__ __forceinline__ u16 bf16b(float f) {
  union { float f; u32 u; } v; v.f = f;
  u32 r = (v.u + 0x7fffu + ((v.u >> 16) & 1u)) >> 16;
  return (u16)r;
}
__device__ __forceinline__ float bf2f(u16 v) {
  union { u32 u; float f; } x; x.u = (u32)v << 16; return x.f;
}
__device__ __forceinline__ f32x4 mfma16(bf16x8 a, bf16x8 b, f32x4 c) {
  return __builtin_amdgcn_mfma_f32_16x16x32_bf16(a, b, c, 0, 0, 0);
}
// async global->LDS DMA, 16B per lane: LDS dest = wave-uniform base + lane*16B,
// global src per-lane (carries the swizzle).
__device__ __forceinline__ void gl_lds16(const u16* g, u16* l) {
  __builtin_amdgcn_global_load_lds(
      (const __attribute__((address_space(1))) void*)g,
      (__attribute__((address_space(3))) void*)l, 16, 0, 0);
}

// ---------------------------------------------------------------- zero-fill (ws-too-small signature)
__global__ __launch_bounds__(256) void zerok(float* __restrict__ p, long n)
{
  long i = ((long)blockIdx.x * 256 + threadIdx.x) * 4;
  if (i < n) { p[i] = 0.f; p[i+1] = 0.f; p[i+2] = 0.f; p[i+3] = 0.f; }
}

// ---------------------------------------------------------------- cast fp32->bf16
__global__ __launch_bounds__(256) void castk(const float* __restrict__ src,
                                             u16* __restrict__ dst, long n)
{
  long i = ((long)blockIdx.x * 256 + threadIdx.x) * 4;
  if (i >= n) return;
  const float4 f = *(const float4*)(src + i);
  uint2 v;
  v.x = (u32)bf16b(f.x) | ((u32)bf16b(f.y) << 16);
  v.y = (u32)bf16b(f.z) | ((u32)bf16b(f.w) << 16);
  *(uint2*)(dst + i) = v;
}

// ---------------------------------------------------------------- split wkv_b
__global__ __launch_bounds__(256) void wsplit(const float* __restrict__ wb,
                                              u16* __restrict__ T1, u16* __restrict__ Wv)
{
  const long i = (long)blockIdx.x * 256 + threadIdx.x;   // < 16*65536
  const int h   = (int)(i >> 16);
  const int rem = (int)(i & 65535);
  { const int c = rem >> 7, d = rem & 127;
    T1[i] = bf16b(wb[((long)(h * 256 + d)) * 512 + c]); }
  { const int d = rem >> 9, c = rem & 511;
    Wv[i] = bf16b(wb[((long)(h * 256 + 128 + d)) * 512 + c]); }
}

// ---------------------------------------------------------------- generic bf16 GEMM  C = A @ W^T
template<int OUTBF>
__global__ __launch_bounds__(256, 2)
void gemm_bt(const u16* __restrict__ A, const u16* __restrict__ W, void* __restrict__ Cout,
             int M, int N, int K, int lda, int ldw, int ldc,
             long aStride, long wStride, long cStride)
{
  __shared__ u16 As[128 * 40];
  __shared__ u16 Bs[128 * 40];
  const int tid = threadIdx.x;
  const int wave = tid >> 6, lane = tid & 63, g = lane >> 4, l15 = lane & 15;
  const int z = blockIdx.z;
  A += (long)z * aStride;  W += (long)z * wStride;
  const long cOff = (long)z * cStride;
  const int m0 = blockIdx.y * 128, n0 = blockIdx.x * 128;
  const int mq = (wave >> 1) * 64, nq = (wave & 1) * 64;
  const int srow = tid >> 1, scol = (tid & 1) * 16;

  const f32x4 fzero = {0.f, 0.f, 0.f, 0.f};
  f32x4 acc[4][4];
#pragma unroll
  for (int i = 0; i < 4; i++)
#pragma unroll
    for (int j = 0; j < 4; j++) acc[i][j] = fzero;

  for (int k0 = 0; k0 < K; k0 += 32) {
    const u16* aSrc = A + (long)(m0 + srow) * lda + k0 + scol;
    uint4 av0 = *(const uint4*)aSrc;
    uint4 av1 = *(const uint4*)(aSrc + 8);
    uint4 bv0 = make_uint4(0, 0, 0, 0), bv1 = make_uint4(0, 0, 0, 0);
    if (n0 + srow < N) {
      const u16* wSrc = W + (long)(n0 + srow) * ldw + k0 + scol;
      bv0 = *(const uint4*)wSrc;
      bv1 = *(const uint4*)(wSrc + 8);
    }
    __syncthreads();
    *(uint4*)&As[srow * 40 + scol]     = av0;
    *(uint4*)&As[srow * 40 + scol + 8] = av1;
    *(uint4*)&Bs[srow * 40 + scol]     = bv0;
    *(uint4*)&Bs[srow * 40 + scol + 8] = bv1;
    __syncthreads();

    bf16x8 af[4], bfr[4];
#pragma unroll
    for (int i = 0; i < 4; i++) af[i]  = *(const bf16x8*)&As[(mq + i * 16 + l15) * 40 + g * 8];
#pragma unroll
    for (int j = 0; j < 4; j++) bfr[j] = *(const bf16x8*)&Bs[(nq + j * 16 + l15) * 40 + g * 8];
#pragma unroll
    for (int i = 0; i < 4; i++)
#pragma unroll
      for (int j = 0; j < 4; j++)
        acc[i][j] = mfma16(af[i], bfr[j], acc[i][j]);
  }

#pragma unroll
  for (int i = 0; i < 4; i++) {
    const int r0 = m0 + mq + i * 16 + g * 4;
#pragma unroll
    for (int j = 0; j < 4; j++) {
      const int c = n0 + nq + j * 16 + l15;
      if (c < N) {
#pragma unroll
        for (int r = 0; r < 4; r++) {
          const long idx = cOff + (long)(r0 + r) * ldc + c;
          if (OUTBF) ((u16*)Cout)[idx]   = bf16b(acc[i][j][r]);
          else       ((float*)Cout)[idx] = acc[i][j][r];
        }
      }
    }
  }
}

// ---------------------------------------------------------------- q rope pack
__global__ __launch_bounds__(256) void qpack(const u16* __restrict__ q,
                                             const float* __restrict__ angles,
                                             u16* __restrict__ qpe)
{
  const int s = blockIdx.x;
  const int sseq = s & (SS - 1);
  const int tid = threadIdx.x;
#pragma unroll
  for (int pp = 0; pp < 2; pp++) {
    const int p = tid * 2 + pp;           // 0..511 pair index
    const int h = p >> 5, j = p & 31;
    const float xr = bf2f(q[(long)s * 3072 + h * 192 + 128 + 2 * j]);
    const float xi = bf2f(q[(long)s * 3072 + h * 192 + 128 + 2 * j + 1]);
    float sn, cs;
    __sincosf(angles[sseq * 32 + j], &sn, &cs);
    const u32 pk = (u32)bf16b(xr * cs - xi * sn) | ((u32)bf16b(xr * sn + xi * cs) << 16);
    *(u32*)(qpe + ((long)s * NH + h) * 64 + 2 * j) = pk;
  }
}

// ---------------------------------------------------------------- kv pack
__global__ __launch_bounds__(256) void kvpack(const u16* __restrict__ kv,
                                              const float* __restrict__ angles,
                                              const float* __restrict__ kvw,
                                              u16* __restrict__ cb, u16* __restrict__ kpe)
{
  const int row = blockIdx.x * 4 + (threadIdx.x >> 6);
  const int lane = threadIdx.x & 63;
  const int sseq = row & (SS - 1);
  const u16* src = kv + (long)row * 576;
  float v[8]; float ss = 0.f;
#pragma unroll
  for (int j = 0; j < 8; j++) { float t = bf2f(src[lane + j * 64]); v[j] = t; ss += t * t; }
#pragma unroll
  for (int d = 1; d < 64; d <<= 1) ss += __shfl_xor(ss, d, 64);
  const float rn = 1.0f / sqrtf(ss * (1.f / 512.f) + 1e-6f);
#pragma unroll
  for (int j = 0; j < 8; j++)
    cb[(long)row * 512 + lane + j * 64] = bf16b(v[j] * rn * kvw[lane + j * 64]);
  if (lane < 32) {
    const float xr = bf2f(src[512 + 2 * lane]), xi = bf2f(src[512 + 2 * lane + 1]);
    float sn, cs;
    __sincosf(angles[sseq * 32 + lane], &sn, &cs);
    const u32 pk = (u32)bf16b(xr * cs - xi * sn) | ((u32)bf16b(xr * sn + xi * cs) << 16);
    *(u32*)(kpe + (long)row * 64 + 2 * lane) = pk;
  }
}

// ---------------------------------------------------------------- MFMA flash attention
// R2-verified compute core (K=32 PV + zero-padded Ps/VT, dbuf DMA K staging,
// defer-max, dual sacc) with:
//  * PAIRED Q-TILES: each block runs q-tile (31-p) then p -> exactly 132
//    steps per block. Grid = 512 = exactly 2 blocks/CU, ALL co-resident ->
//    tail-free makespan, independent of dispatch order (R4 lesson: x-fastest
//    dispatch defeats any order trick).
//  * XCD-PINNED BATCH: xcd = blockIdx%8 (measured round-robin), b = bit2 of
//    blockIdx -> each XCD serves ONE b, whose K/V working set (2.35 MB) fits
//    its 4 MB L2. This removes R3's pairing-misalignment HBM thrash (1.2 GB
//    FETCH): misaligned tile reads now hit L2, not HBM.
// Half-boundary safety (proven in R3): nsteps ≡ 0 mod 4 -> last step reads
// buf 1; next half's prologue DMA writes buf 0; barrier1 of the next half
// orders VT reuse.
__global__ __launch_bounds__(256, 2)
void attn_flash(const u16* __restrict__ qab, const u16* __restrict__ qpe,
                const u16* __restrict__ cb, const u16* __restrict__ kpe,
                u16* __restrict__ olat)
{
  __shared__ u16 KsD[2][16 * 512];   // 32768 B  K c-part, dbuf, content-swizzled
  __shared__ u16 KrD[2][16 * 64];    //  4096 B  K rope,  dbuf, content-swizzled
  __shared__ u16 VT[512 * 32];       // 32768 B  [c][t'] bijective-swizzled; t' 16..31 stay 0
  __shared__ u16 Ps[4][16 * 40];     //  5120 B  per-wave P[s'][t'], cols 16..39 stay 0

  const int tid = threadIdx.x;
  const int wave = tid >> 6, lane = tid & 63;
  const int g = lane >> 4, l15 = lane & 15;
  const int L = blockIdx.x;                  // 0..511
  const int b = (L >> 2) & 1;                // xcd = L%8 -> XCDs 0-3: b=0, 4-7: b=1
  const int u = ((L >> 3) << 2) | (L & 3);   // 0..255, bijective with (L>>3, L&3)
  const int h = u & 15;
  const int p = u >> 4;                      // 0..15 -> pair (31-p, p)
  const float NEG_INF = -__builtin_inff();
  const float SC = 0.07216878364870323f * 1.3688879454113936f * 1.3688879454113936f;
  const f32x4 fzero = {0.f, 0.f, 0.f, 0.f};

  // zero-init Ps pad cols and full VT once (unwritten swizzle slots must be
  // 0.0: they feed PV's k=16..31 region where Ps is 0 -> 0*finite = 0)
  for (int idx = tid; idx < 4 * 16 * 40 / 2; idx += 256) ((u32*)Ps)[idx] = 0;
  for (int idx = tid; idx < 512 * 32 / 2;   idx += 256) ((u32*)VT)[idx] = 0;

  const int tp   = tid & 7;        // VT build: t-pair 0..7
  const int cblk = tid >> 3;       // VT build: c-block 0..31 (16 c each)

  // ---- DMA issue for tile at row-offset t0n into buffer `buf` (wave-divided)
  auto stage = [&](int t0n, int buf) {
#pragma unroll
    for (int it = 0; it < 4; ++it) {
      const int tr = it * 4 + wave;                       // K row 0..15, 4 per wave
      const int sw = ((tr >> 1) & 7) << 3;
      const u16* gp = cb + (long)(b * SS + t0n + tr) * 512 + ((lane * 8) ^ sw);
      gl_lds16(gp, &KsD[buf][tr * 512]);                  // lane fills 16B chunk lane
    }
    if (wave < 2) {                                        // rope: 8 rows per wave
      const int r0 = wave * 8;
      const int tr = r0 + (lane >> 3);
      const int sw = ((tr >> 1) & 7) << 3;
      const u16* gp = kpe + (long)(b * SS + t0n + tr) * 64 + (((lane & 7) * 8) ^ sw);
      gl_lds16(gp, &KrD[buf][r0 * 64]);
    }
  };

#pragma unroll 1
  for (int half = 0; half < 2; ++half) {
    const int qt = half ? p : (31 - p);      // heavy q-tile first
    const int swave = qt * 64 + wave * 16;

    // Q A-fragments: A[m=l15][k=g*8+j], k over 576 = 18 frags
    bf16x8 qf[18];
    {
      const u16* qa = qab + ((long)(b * SS + swave + l15) * NH + h) * 512;
#pragma unroll
      for (int f = 0; f < 16; f++) qf[f] = *(const bf16x8*)(qa + f * 32 + g * 8);
      const u16* qp = qpe + ((long)(b * SS + swave + l15) * NH + h) * 64;
      qf[16] = *(const bf16x8*)(qp + g * 8);
      qf[17] = *(const bf16x8*)(qp + 32 + g * 8);
    }

    f32x4 oacc[32];                 // O[s'=g*4+r][c=i*16+l15]
#pragma unroll
    for (int i = 0; i < 32; i++) oacc[i] = fzero;
    float m[4], l[4];
#pragma unroll
    for (int r = 0; r < 4; r++) { m[r] = NEG_INF; l[r] = 0.f; }

    const int nsteps  = 4 * qt + 4;
    const int lastact = 4 * qt + wave;   // last tile this wave needs

    stage(0, 0);                      // prologue: tile 0 -> buf 0

    for (int ts = 0; ts < nsteps; ++ts) {
      const int cur = ts & 1;
      const int t0 = ts * 16;
      // consume point: own DMA landed; barrier makes all waves' DMA + prior
      // compute (last readers of VT and KsD[cur^1]) visible.
      asm volatile("s_waitcnt vmcnt(0) lgkmcnt(0)" ::: "memory");
      __builtin_amdgcn_s_barrier();

      if (ts + 1 < nsteps) stage(t0 + 16, cur ^ 1);   // prefetch; in flight through compute

      // ---- build VT from resident K tile (LDS->LDS transpose, static scatter)
      {
        const u16* K0 = &KsD[cur][(2 * tp) * 512];
        const u16* K1 = &KsD[cur][(2 * tp + 1) * 512];
        const int swr  = (tp & 7) << 3;                 // sw(2tp) == sw(2tp+1)
        const int cb16 = cblk * 16;
        const bf16x8 alo = *(const bf16x8*)&K0[(cb16)     ^ swr];
        const bf16x8 ahi = *(const bf16x8*)&K0[(cb16 + 8) ^ swr];
        const bf16x8 blo = *(const bf16x8*)&K1[(cb16)     ^ swr];
        const bf16x8 bhi = *(const bf16x8*)&K1[(cb16 + 8) ^ swr];
#pragma unroll
        for (int j = 0; j < 16; ++j) {                  // j static -> register extracts
          const int c = cb16 + j;
          const u16 ua = (u16)((j < 8) ? alo[j] : ahi[j - 8]);
          const u16 ub = (u16)((j < 8) ? blo[j] : bhi[j - 8]);
          *(u32*)&VT[(c * 32 + 2 * tp) ^ ((cblk & 7) << 3)] = (u32)ua | ((u32)ub << 16);
        }
      }
      asm volatile("s_waitcnt lgkmcnt(0)" ::: "memory");   // VT writes done (vmcnt untouched!)
      __builtin_amdgcn_s_barrier();

      if (ts > lastact) continue;        // wave-uniform; barriers still hit each iter

      // ---- S = Q K^T : dual accumulators halve the dependent-MFMA chain
      const int swl = ((l15 >> 1) & 7) << 3;
      const u16* KsC = &KsD[cur][l15 * 512];
      const u16* KrC = &KrD[cur][l15 * 64];
      f32x4 sacc = fzero, sacc2 = fzero;
      __builtin_amdgcn_s_setprio(1);
#pragma unroll
      for (int f = 0; f < 16; f += 2) {
        const bf16x8 k0 = *(const bf16x8*)&KsC[((f    ) * 32 + g * 8) ^ swl];
        const bf16x8 k1 = *(const bf16x8*)&KsC[((f + 1) * 32 + g * 8) ^ swl];
        sacc  = mfma16(qf[f],     k0, sacc);
        sacc2 = mfma16(qf[f + 1], k1, sacc2);
      }
      {
        const bf16x8 k0 = *(const bf16x8*)&KrC[(     g * 8) ^ swl];
        const bf16x8 k1 = *(const bf16x8*)&KrC[(32 + g * 8) ^ swl];
        sacc  = mfma16(qf[16], k0, sacc);
        sacc2 = mfma16(qf[17], k1, sacc2);
      }
      __builtin_amdgcn_s_setprio(0);

      // ---- online softmax with defer-max (THR=8): keep old m unless tile max
      // jumps by >8 -> rescale pass (below) skipped on most steps.
      float alf[4]; bool resc = false;
#pragma unroll
      for (int r = 0; r < 4; ++r) {
        const int srow = swave + g * 4 + r;
        float v = (sacc[r] + sacc2[r]) * SC;
        if (t0 + l15 > srow) v = NEG_INF;
        float tm = v;
#pragma unroll
        for (int d = 1; d < 16; d <<= 1) tm = fmaxf(tm, __shfl_xor(tm, d, 64));
        const float mnew = (tm > m[r] + 8.f) ? tm : m[r];   // m=-inf: -inf+8=-inf -> take tm
        const float al = __expf(m[r] - mnew);               // 1.0 when unchanged
        const float pv = __expf(v - mnew);                  // bounded by e^8; masked: 0
        float rs = pv;
#pragma unroll
        for (int d = 1; d < 16; d <<= 1) rs += __shfl_xor(rs, d, 64);
        l[r] = l[r] * al + rs;
        resc |= (mnew != m[r]);
        m[r] = mnew;
        alf[r] = al;
        Ps[wave][(g * 4 + r) * 40 + l15] = bf16b(pv);   // intra-wave LDS, no barrier
      }

      // ---- gated rescale (skipped when no row max moved anywhere in the wave)
      if (__any((int)resc)) {
#pragma unroll
        for (int i = 0; i < 32; ++i) {
          f32x4 o = oacc[i];
          o[0] *= alf[0]; o[1] *= alf[1]; o[2] *= alf[2]; o[3] *= alf[3];
          oacc[i] = o;
        }
      }

      // ---- O += P.V : A[m=s'][k=t' (0-pad 16..31)], B from bijective-swizzled VT
      const bf16x8 paf = *(const bf16x8*)&Ps[wave][l15 * 40 + g * 8];
      __builtin_amdgcn_s_setprio(1);
#pragma unroll
      for (int i = 0; i < 32; ++i) {
        const int c = i * 16 + l15;
        const bf16x8 vf = *(const bf16x8*)&VT[(c * 32 + g * 8) ^ ((i & 7) << 3)];
        oacc[i] = mfma16(paf, vf, oacc[i]);
      }
      __builtin_amdgcn_s_setprio(0);
    }

    // ---- epilogue: O[s][c] / l[s]
    float linv[4];
#pragma unroll
    for (int r = 0; r < 4; ++r) linv[r] = 1.0f / l[r];
#pragma unroll
    for (int r = 0; r < 4; ++r) {
      u16* dst = olat + ((long)(b * SS + swave + g * 4 + r) * NH + h) * 512 + l15;
#pragma unroll
      for (int i = 0; i < 32; ++i)
        dst[i * 16] = bf16b(oacc[i][r] * linv[r]);
    }
  }
}

// ---------------------------------------------------------------- launch
extern "C" void kernel_launch(void* const* d_in, const int* in_sizes, int n_in,
                              void* d_out, int out_size, void* d_ws, size_t ws_size,
                              hipStream_t stream)
{
  const float* x      = (const float*)d_in[0];
  const float* angles = (const float*)d_in[1];
  const float* wq     = (const float*)d_in[2];
  const float* wkv_a  = (const float*)d_in[3];
  const float* wkv_b  = (const float*)d_in[4];
  const float* wo     = (const float*)d_in[5];
  const float* kvw    = (const float*)d_in[6];

  // --- workspace plan (byte offsets; lifetimes audited against launch order) ---
  const size_t WS_NEED = 157810688;
  if (ws_size < WS_NEED) {           // observable signature: err == ref absmax (3.890625)
    zerok<<<dim3(8192), dim3(256), 0, stream>>>((float*)d_out, 8388608L);
    return;
  }
  char* base = (char*)d_ws;
  u16* xb   = (u16*)(base + 0);           // 16,777,216 B  [4096][2048]   dead after kv GEMM
  u16* kvb  = (u16*)(base + 16777216);    //  4,718,592 B  [4096][576]    dead after kvpack
  u16* wab  = (u16*)(base + 21495808);    //  2,359,296 B  [576][2048]    dead after kv GEMM
  u16* qab  = (u16*)(base + 0);           // 67,108,864 B  [4096][16][512]  (phase2 of A)
  u16* ob   = (u16*)(base + 0);           // 16,777,216 B  [4096][2048]     (phase3 of A)
  u16* qbf  = (u16*)(base + 67108864);    // 25,165,824 B  [4096][3072]   dead after absorb GEMM
  u16* T1   = (u16*)(base + 92274688);    //  2,097,152 B  [16][512][128] dead after absorb GEMM
  u16* wqb  = (u16*)(base + 94371840);    // 12,582,912 B  [3072][2048]   dead after q GEMM
  u16* olat = (u16*)(base + 67108864);    // 67,108,864 B  [4096][16][512]  (phase2 of B)
  u16* wob  = (u16*)(base + 134217728);   //  8,388,608 B  [2048][2048]
  u16* Wv   = (u16*)(base + 142606336);   //  2,097,152 B  [16][128][512]
  u16* qpe_ = (u16*)(base + 144703488);   //  8,388,608 B  [4096][16][64]
  u16* cbuf = (u16*)(base + 153092096);   //  4,194,304 B  [4096][512]
  u16* kpeb = (u16*)(base + 157286400);   //    524,288 B  [4096][64]

  castk<<<dim3(8192), dim3(256), 0, stream>>>(x, xb, 8388608L);
  castk<<<dim3(6144), dim3(256), 0, stream>>>(wq, wqb, 6291456L);
  castk<<<dim3(1152), dim3(256), 0, stream>>>(wkv_a, wab, 1179648L);
  castk<<<dim3(4096), dim3(256), 0, stream>>>(wo, wob, 4194304L);
  wsplit<<<dim3(4096), dim3(256), 0, stream>>>(wkv_b, T1, Wv);

  // q = x @ wq^T (bf16 out) ; kv = x @ wkv_a^T (bf16 out)
  gemm_bt<1><<<dim3(24, 32, 1), dim3(256), 0, stream>>>(
      xb, wqb, (void*)qbf, 4096, 3072, 2048, 2048, 2048, 3072, 0L, 0L, 0L);
  gemm_bt<1><<<dim3(5, 32, 1), dim3(256), 0, stream>>>(
      xb, wab, (void*)kvb, 4096, 576, 2048, 2048, 2048, 576, 0L, 0L, 0L);

  qpack<<<dim3(4096), dim3(256), 0, stream>>>(qbf, angles, qpe_);
  kvpack<<<dim3(1024), dim3(256), 0, stream>>>(kvb, angles, kvw, cbuf, kpeb);

  // q_abs[s][h][c] = q_nope[s][h][:] @ T1[h][c][:]
  gemm_bt<1><<<dim3(4, 32, 16), dim3(256), 0, stream>>>(
      qbf, T1, (void*)qab, 4096, 512, 128, 3072, 128, 8192, 192L, 65536L, 512L);

  attn_flash<<<dim3(512, 1), dim3(256), 0, stream>>>(qab, qpe_, cbuf, kpeb, olat);

  // o[s][h][d] = olat[s][h][:] @ Wv[h][d][:]
  gemm_bt<1><<<dim3(1, 32, 16), dim3(256), 0, stream>>>(
      olat, Wv, (void*)ob, 4096, 128, 512, 8192, 512, 2048, 512L, 65536L, 128L);

  // out = ob @ wo^T
  gemm_bt<0><<<dim3(16, 32, 1), dim3(256), 0, stream>>>(
      ob, wob, d_out, 4096, 2048, 2048, 2048, 2048, 2048, 0L, 0L, 0L);
}